// Round 10
// baseline (3076.248 us; speedup 1.0000x reference)
//
#include <hip/hip_runtime.h>

// x [16384,512] f32, codebook [8192,512] f32 -> out[n] = codebook[argmin_k ||x_n-c_k||^2]
// int8 MFMA GEMM (16x16x64 i8, exact i32 accum) with read-ahead pipeline + 3-buffer LDS;
// per-row symmetric quantization with deterministic error bounds; per-lane register top-3
// filter; guaranteed-inclusive fp64 refinement (+fused gather); gather fallback.

#define MROWS 16384
#define KCB   8192
#define DDIM  512
#define NTILES 64            // stat tiles of 128 cb rows

typedef unsigned short u16;
typedef unsigned int uint;
typedef signed char i8;
typedef __attribute__((ext_vector_type(4))) int i32x4;

__device__ inline void gload16(const void* g, void* l) {
  __builtin_amdgcn_global_load_lds((const __attribute__((address_space(1))) void*)g,
                                   (__attribute__((address_space(3))) void*)l,
                                   16, 0, 0);
}

__device__ inline double shfl_xor_dbl(double v, int m) {
  long long l = __double_as_longlong(v);
  int lo = (int)(l & 0xffffffffLL), hi = (int)(l >> 32);
  lo = __shfl_xor(lo, m, 64);
  hi = __shfl_xor(hi, m, 64);
  return __longlong_as_double(((long long)hi << 32) | (unsigned long long)(unsigned int)lo);
}

__device__ inline float keyval(uint k) {
  uint u = k & 0xFFFFFF80u;
  uint bits = (u & 0x80000000u) ? (u & 0x7FFFFFFFu) : ~u;
  return __uint_as_float(bits);
}

// ---------------- quantization kernels ----------------

__global__ __launch_bounds__(256) void k_quant_x(const float* __restrict__ x,
                                                 i8* __restrict__ Xi8,
                                                 float* __restrict__ sxA,
                                                 float* __restrict__ AxA,
                                                 uint* __restrict__ zeroT) {
  if (blockIdx.x == 0 && threadIdx.x < 128) zeroT[threadIdx.x] = 0;  // zero scT/CsT
  int n = blockIdx.x * 4 + (threadIdx.x >> 6);
  int lane = threadIdx.x & 63;
  const float* xr = x + (size_t)n * DDIM + lane * 8;
  float4 a = *(const float4*)xr;
  float4 b = *(const float4*)(xr + 4);
  float v[8] = {a.x, a.y, a.z, a.w, b.x, b.y, b.z, b.w};
  float amax = 0.f, asum = 0.f;
  #pragma unroll
  for (int i = 0; i < 8; ++i) { float f = fabsf(v[i]); amax = fmaxf(amax, f); asum += f; }
  #pragma unroll
  for (int m = 1; m < 64; m <<= 1) {
    amax = fmaxf(amax, __shfl_xor(amax, m, 64));
    asum += __shfl_xor(asum, m, 64);
  }
  amax = fmaxf(amax, 1e-20f);
  float inv = 127.0f / amax;
  int q[8];
  #pragma unroll
  for (int i = 0; i < 8; ++i) {
    int t = __float2int_rn(v[i] * inv);
    q[i] = min(127, max(-127, t));
  }
  uint lo = (q[0] & 255) | ((q[1] & 255) << 8) | ((q[2] & 255) << 16) | ((uint)(q[3] & 255) << 24);
  uint hi = (q[4] & 255) | ((q[5] & 255) << 8) | ((q[6] & 255) << 16) | ((uint)(q[7] & 255) << 24);
  ((uint2*)(Xi8 + (size_t)n * DDIM))[lane] = make_uint2(lo, hi);
  if (lane == 0) { sxA[n] = amax * (1.0f / 127.0f); AxA[n] = asum; }
}

__global__ __launch_bounds__(256) void k_quant_c(const float* __restrict__ cb,
                                                 i8* __restrict__ Ci8,
                                                 float* __restrict__ scA,
                                                 float* __restrict__ cnormA,
                                                 uint* __restrict__ scT,
                                                 uint* __restrict__ CsT) {
  int k = blockIdx.x * 4 + (threadIdx.x >> 6);
  int lane = threadIdx.x & 63;
  const float* cr = cb + (size_t)k * DDIM + lane * 8;
  float4 a = *(const float4*)cr;
  float4 b = *(const float4*)(cr + 4);
  float v[8] = {a.x, a.y, a.z, a.w, b.x, b.y, b.z, b.w};
  float amax = 0.f, asum = 0.f, sq = 0.f;
  #pragma unroll
  for (int i = 0; i < 8; ++i) { float f = fabsf(v[i]); amax = fmaxf(amax, f); asum += f; sq += v[i]*v[i]; }
  #pragma unroll
  for (int m = 1; m < 64; m <<= 1) {
    amax = fmaxf(amax, __shfl_xor(amax, m, 64));
    asum += __shfl_xor(asum, m, 64);
    sq   += __shfl_xor(sq, m, 64);
  }
  amax = fmaxf(amax, 1e-20f);
  float inv = 127.0f / amax;
  int q[8];
  #pragma unroll
  for (int i = 0; i < 8; ++i) {
    int t = __float2int_rn(v[i] * inv);
    q[i] = min(127, max(-127, t));
  }
  uint lo = (q[0] & 255) | ((q[1] & 255) << 8) | ((q[2] & 255) << 16) | ((uint)(q[3] & 255) << 24);
  uint hi = (q[4] & 255) | ((q[5] & 255) << 8) | ((q[6] & 255) << 16) | ((uint)(q[7] & 255) << 24);
  ((uint2*)(Ci8 + (size_t)k * DDIM))[lane] = make_uint2(lo, hi);
  if (lane == 0) {
    float sc = amax * (1.0f / 127.0f);
    scA[k] = sc;
    cnormA[k] = sq;
    atomicMax(&scT[k >> 7], __float_as_uint(sc));
    atomicMax(&CsT[k >> 7], __float_as_uint(asum));
  }
}

// ---------------- 256x256 i8 GEMM, read-ahead + 3-buffer LDS ----------------
// LDS bytes: buf b at b*32768: A at +0 (unit u at +u*8192: slot wr at +wr*4096),
// B at +16384 (unit v at +v*8192). Rowwise XOR-4 16B-chunk swizzle on source.

__global__ __launch_bounds__(512, 2) void k_gemm_min(
    const i8* __restrict__ Xi8, const i8* __restrict__ Ci8,
    const float* __restrict__ scA, const float* __restrict__ cnormA,
    const float* __restrict__ sxA, uint2* __restrict__ stats)
{
  extern __shared__ __align__(16) char lds[];

  int bid = blockIdx.x;          // 2048 blocks
  int xcd = bid & 7;
  int j   = bid >> 3;
  int mTile = xcd * 8 + (j & 7); // x tiles 0..63
  int nTile = j >> 3;            // cb tiles 0..31
  int rowBase = mTile * 256;     // x rows
  int colBase = nTile * 256;     // cb rows

  int tid = threadIdx.x;
  int lane = tid & 63;
  int wv = tid >> 6;     // 0..7
  int wr = wv >> 2;      // 0..1  cb half (M)
  int wc = wv & 3;       // 0..3  x quarter (N)
  int grp = lane >> 4;
  int l15 = lane & 15;

  // stage source base (inverse-swizzled 16B chunk)
  const int pcsw = ((tid & 3) ^ ((tid >> 2) & 3)) * 16;
  const i8* pA = Ci8 + (size_t)(colBase + (tid >> 8) * 128 + ((tid >> 2) & 63)) * DDIM + pcsw;
  const i8* pB = Xi8 + (size_t)(rowBase + (tid >> 2)) * DDIM + pcsw;

  // reader LDS byte offsets
  const int swz = (grp ^ (l15 & 3)) * 16;
  const int cBase = wr * 4096 + l15 * 64 + swz;
  const int xBase = 16384 + wc * 4096 + l15 * 64 + swz;

  i32x4 acc[8][4];
  #pragma unroll
  for (int mi = 0; mi < 8; ++mi)
    #pragma unroll
    for (int ni = 0; ni < 4; ++ni)
      acc[mi][ni] = (i32x4){0, 0, 0, 0};

  i32x4 cF[2][4], xF[2][4];

#define SA(T, u) gload16(pA + (u) * 32768 + (T) * 64, \
                         (void*)(lds + ((T) % 3) * 32768 + (u) * 8192 + tid * 16))
#define SB(T, v) gload16(pB + (v) * 65536 + (T) * 64, \
                         (void*)(lds + ((T) % 3) * 32768 + 16384 + (v) * 8192 + tid * 16))

#define ISSUE_READS(pp)                                                                  \
  { const int kt_ = (pp) >> 1, h_ = (pp) & 1;                                            \
    const char* bb_ = lds + (kt_ % 3) * 32768;                                           \
    _Pragma("unroll")                                                                    \
    for (int q = 0; q < 4; ++q)                                                          \
      cF[(pp) & 1][q] = *(const i32x4*)(bb_ + h_ * 8192 + q * 1024 + cBase);             \
    if (h_ == 0) {                                                                       \
      _Pragma("unroll")                                                                  \
      for (int ni = 0; ni < 4; ++ni)                                                     \
        xF[kt_ & 1][ni] = *(const i32x4*)(bb_ + ni * 1024 + xBase);                      \
    } }

  // ---- prologue: tiles 0,1 fully staged; certify tile 0; reads(0) ----
  SA(0, 0); SA(0, 1); SB(0, 0); SB(0, 1);
  SA(1, 0); SA(1, 1); SB(1, 0); SB(1, 1);
  asm volatile("s_waitcnt vmcnt(4)" ::: "memory");
  __builtin_amdgcn_s_barrier();
  __builtin_amdgcn_sched_barrier(0);
  ISSUE_READS(0);

  #pragma unroll
  for (int ph = 0; ph < 16; ++ph) {
    const int kt = ph >> 1, h = ph & 1;

    // counted certification (drains tile kt+1's 4 units; leaves newest 2)
    if ((ph & 1) && ph < 13)  asm volatile("s_waitcnt vmcnt(2)" ::: "memory");
    if (ph == 13)             asm volatile("s_waitcnt vmcnt(0)" ::: "memory");
    __builtin_amdgcn_s_barrier();
    __builtin_amdgcn_sched_barrier(0);

    // stage tile kt+2 (A pair on even phase, B pair on odd); buf (kt+2)%3 is
    // disjoint from both read buffers -> no overwrite hazard at skew<1 phase.
    if (h == 0) { if (kt + 2 <= 7) { SA(kt + 2, 0); SA(kt + 2, 1); } }
    else        { if (kt + 2 <= 7) { SB(kt + 2, 0); SB(kt + 2, 1); } }

    // read-ahead for ph+1 into alternate register set
    if (ph < 15) ISSUE_READS(ph + 1);

    // drain reads(ph), keep reads(ph+1) outstanding
    if (ph == 15)      asm volatile("s_waitcnt lgkmcnt(0)" ::: "memory");
    else if (h == 0)   asm volatile("s_waitcnt lgkmcnt(4)" ::: "memory");
    else               asm volatile("s_waitcnt lgkmcnt(8)" ::: "memory");
    __builtin_amdgcn_sched_barrier(0);

    __builtin_amdgcn_s_setprio(1);
    #pragma unroll
    for (int q = 0; q < 4; ++q)
      #pragma unroll
      for (int ni = 0; ni < 4; ++ni)
        acc[h * 4 + q][ni] = __builtin_amdgcn_mfma_i32_16x16x64_i8(
            cF[ph & 1][q], xF[kt & 1][ni], acc[h * 4 + q][ni], 0, 0, 0);
    __builtin_amdgcn_s_setprio(0);
  }
#undef ISSUE_READS
#undef SA
#undef SB

  // ---- epilogue: per-lane register top-3 on approx scores ----
  // D[m=cb][n=x]: x-row = lane&15, cb = (lane>>4)*4 + reg
#define INS(st1, st2, st3, kx)                                     \
  { uint kk_ = (kx);                                               \
    bool lt1 = kk_ < st1, lt2 = kk_ < st2, lt3 = kk_ < st3;        \
    st3 = lt3 ? (lt2 ? st2 : kk_) : st3;                           \
    st2 = lt2 ? (lt1 ? st1 : kk_) : st2;                           \
    st1 = lt1 ? kk_ : st1; }

  float sx2[4];
  #pragma unroll
  for (int ni = 0; ni < 4; ++ni)
    sx2[ni] = 2.0f * sxA[rowBase + wc * 64 + ni * 16 + l15];

  uint t1[4], t2[4], t3[4];
  #pragma unroll
  for (int ni = 0; ni < 4; ++ni) { t1[ni] = 0xFFFFFFFFu; t2[ni] = 0xFFFFFFFFu; t3[ni] = 0xFFFFFFFFu; }

  #pragma unroll
  for (int mi = 0; mi < 8; ++mi) {
    int kb = colBase + wr * 128 + mi * 16 + grp * 4;
    float cnv[4], scv[4];
    *(float4*)cnv = *(const float4*)&cnormA[kb];
    *(float4*)scv = *(const float4*)&scA[kb];
    #pragma unroll
    for (int ni = 0; ni < 4; ++ni) {
      #pragma unroll
      for (int rg = 0; rg < 4; ++rg) {
        float v = cnv[rg] - sx2[ni] * scv[rg] * (float)acc[mi][ni][rg];
        uint u = __float_as_uint(v);
        u = ((int)u < 0) ? ~u : (u | 0x80000000u);
        uint key = (u & 0xFFFFFF80u) | (uint)(mi * 16 + grp * 4 + rg);
        INS(t1[ni], t2[ni], t3[ni], key);
      }
    }
  }
  #pragma unroll
  for (int ni = 0; ni < 4; ++ni) {
    #pragma unroll
    for (int mk = 16; mk <= 32; mk <<= 1) {
      uint o1 = (uint)__shfl_xor((int)t1[ni], mk, 64);
      uint o2 = (uint)__shfl_xor((int)t2[ni], mk, 64);
      uint o3 = (uint)__shfl_xor((int)t3[ni], mk, 64);
      INS(t1[ni], t2[ni], t3[ni], o1);
      INS(t1[ni], t2[ni], t3[ni], o2);
      INS(t1[ni], t2[ni], t3[ni], o3);
    }
  }
#undef INS
  if (grp == 0) {
    #pragma unroll
    for (int ni = 0; ni < 4; ++ni) {
      float v1 = keyval(t1[ni]), v2 = keyval(t2[ni]), v3 = keyval(t3[ni]);
      uint i1 = t1[ni] & 127u, i2 = t2[ni] & 127u;
      uint d2 = min(255u, (uint)((v2 - v1) * 4.0f));   // floor -> conservative-low
      uint d3 = min(255u, (uint)((v3 - v1) * 4.0f));
      uint2 st;
      st.x = __float_as_uint(v1);
      st.y = i1 | (i2 << 7) | (d2 << 14) | (d3 << 22);
      int xrow = rowBase + wc * 64 + ni * 16 + l15;
      stats[(size_t)xrow * NTILES + nTile * 2 + wr] = st;
    }
  }
}

// ---------------- fp64 refinement core ----------------

__device__ inline void eval64(const float4& xa, const float4& xb,
                              const float* __restrict__ cb, int col,
                              double& best, int& bi, int lane) {
  const float* cr = cb + (size_t)col * DDIM + lane * 8;
  float4 ca = *(const float4*)cr;
  float4 cv = *(const float4*)(cr + 4);
  double s = 0.0, d;
  d = (double)xa.x - (double)ca.x; s += d*d;
  d = (double)xa.y - (double)ca.y; s += d*d;
  d = (double)xa.z - (double)ca.z; s += d*d;
  d = (double)xa.w - (double)ca.w; s += d*d;
  d = (double)xb.x - (double)cv.x; s += d*d;
  d = (double)xb.y - (double)cv.y; s += d*d;
  d = (double)xb.z - (double)cv.z; s += d*d;
  d = (double)xb.w - (double)cv.w; s += d*d;
  #pragma unroll
  for (int m = 1; m < 64; m <<= 1) s += shfl_xor_dbl(s, m);
  if (s < best || (s == best && col < bi)) { best = s; bi = col; }
}

// Guaranteed-inclusive: per-(row,tile) deterministic quantization error bound
//   E = scTmax * (A_n + 256*sx_n) + sx_n * CsTmax + 0.1
// U = min over tiles of (tileMinApprox + E)  >= true min distance-score.
// Any k with approxScore(k) - E <= U may be the argmin; all others provably not.
__device__ inline int refine_row(int n, int lane,
                                 const float* __restrict__ x, const float* __restrict__ cb,
                                 const float* __restrict__ cnormA,
                                 const float* __restrict__ sxA, const float* __restrict__ AxA,
                                 const float* __restrict__ scT, const float* __restrict__ CsT,
                                 const uint2* __restrict__ stats) {
  uint2 st = stats[(size_t)n * NTILES + lane];   // lane t owns tile t
  float v1 = __uint_as_float(st.x);
  int   i1 = st.y & 127, i2 = (st.y >> 7) & 127;
  float m2 = v1 + ((st.y >> 14) & 255u) * 0.25f;
  float m3 = v1 + ((st.y >> 22) & 255u) * 0.25f;
  float sxn = sxA[n], Axn = AxA[n];
  float E = scT[lane] * (Axn + 256.0f * sxn) + sxn * CsT[lane] + 0.1f;
  float hi = v1 + E;
  float U = hi;
  #pragma unroll
  for (int m = 1; m < 64; m <<= 1) U = fminf(U, __shfl_xor(U, m, 64));
  unsigned long long q1 = __ballot(v1 - E <= U);
  unsigned long long q2 = __ballot(m2 - E <= U);
  unsigned long long qr = __ballot(m3 - E <= U);

  const float* xr = x + (size_t)n * DDIM;
  float4 xa = *(const float4*)(xr + lane * 8);
  float4 xb = *(const float4*)(xr + lane * 8 + 4);

  double best = 1e300;
  int bi = 0x7fffffff;

  while (q1) {
    int t = __ffsll(q1) - 1; q1 &= q1 - 1;
    int col = t * 128 + __shfl(i1, t, 64);
    eval64(xa, xb, cb, col, best, bi, lane);
  }
  while (q2) {
    int t = __ffsll(q2) - 1; q2 &= q2 - 1;
    int col = t * 128 + __shfl(i2, t, 64);
    eval64(xa, xb, cb, col, best, bi, lane);
  }
  while (qr) {
    int t = __ffsll(qr) - 1; qr &= qr - 1;
    for (int c2 = 0; c2 < 128; ++c2) {
      int col2 = t * 128 + c2;
      const float* cr = cb + (size_t)col2 * DDIM + lane * 8;
      float4 ca = *(const float4*)cr;
      float4 cv = *(const float4*)(cr + 4);
      float p = xa.x*ca.x + xa.y*ca.y + xa.z*ca.z + xa.w*ca.w
              + xb.x*cv.x + xb.y*cv.y + xb.z*cv.z + xb.w*cv.w;
      #pragma unroll
      for (int m = 1; m < 64; m <<= 1) p += __shfl_xor(p, m, 64);
      float s32 = cnormA[col2] - 2.0f * p;   // fp32 from originals: err <= ~0.05
      if (s32 <= U + 0.1f) {
        double s = 0.0, dd;
        dd = (double)xa.x - (double)ca.x; s += dd*dd;
        dd = (double)xa.y - (double)ca.y; s += dd*dd;
        dd = (double)xa.z - (double)ca.z; s += dd*dd;
        dd = (double)xa.w - (double)ca.w; s += dd*dd;
        dd = (double)xb.x - (double)cv.x; s += dd*dd;
        dd = (double)xb.y - (double)cv.y; s += dd*dd;
        dd = (double)xb.z - (double)cv.z; s += dd*dd;
        dd = (double)xb.w - (double)cv.w; s += dd*dd;
        #pragma unroll
        for (int m = 1; m < 64; m <<= 1) s += shfl_xor_dbl(s, m);
        if (s < best || (s == best && col2 < bi)) { best = s; bi = col2; }
      }
    }
  }
  return bi;
}

__global__ __launch_bounds__(256) void k_refine(
    const float* __restrict__ x, const float* __restrict__ cb,
    const float* __restrict__ cnormA, const float* __restrict__ sxA,
    const float* __restrict__ AxA, const float* __restrict__ scT,
    const float* __restrict__ CsT, const uint2* __restrict__ stats,
    unsigned int* __restrict__ bestOut)
{
  int n = blockIdx.x * 4 + (threadIdx.x >> 6);
  int lane = threadIdx.x & 63;
  int bi = refine_row(n, lane, x, cb, cnormA, sxA, AxA, scT, CsT, stats);
  if (lane == 0) bestOut[n] = (unsigned int)bi;
}

__global__ __launch_bounds__(256) void k_refine_gather(
    const float* __restrict__ x, const float* __restrict__ cb,
    const float* __restrict__ cnormA, const float* __restrict__ sxA,
    const float* __restrict__ AxA, const float* __restrict__ scT,
    const float* __restrict__ CsT, const uint2* __restrict__ stats,
    float* __restrict__ out)
{
  int n = blockIdx.x * 4 + (threadIdx.x >> 6);
  int lane = threadIdx.x & 63;
  int bi = refine_row(n, lane, x, cb, cnormA, sxA, AxA, scT, CsT, stats);
  const float4* s = (const float4*)(cb + (size_t)bi * DDIM);
  float4* dp = (float4*)(out + (size_t)n * DDIM);
  dp[lane * 2]     = s[lane * 2];
  dp[lane * 2 + 1] = s[lane * 2 + 1];
}

__global__ __launch_bounds__(256) void k_gather(const float* __restrict__ cb,
                                                const unsigned int* __restrict__ bestIdx,
                                                float* __restrict__ out) {
  int n = blockIdx.x * 4 + (threadIdx.x >> 6);
  int lane = threadIdx.x & 63;
  unsigned int b = bestIdx[n];
  const float4* s = (const float4*)(cb + (size_t)b * DDIM);
  float4* dp = (float4*)(out + (size_t)n * DDIM);
  dp[lane * 2]     = s[lane * 2];
  dp[lane * 2 + 1] = s[lane * 2 + 1];
}

// ---------------- launch ----------------

extern "C" void kernel_launch(void* const* d_in, const int* in_sizes, int n_in,
                              void* d_out, int out_size, void* d_ws, size_t ws_size,
                              hipStream_t stream) {
  const float* x  = (const float*)d_in[0];   // [16384, 512]
  const float* cb = (const float*)d_in[1];   // [8192, 512]
  float* out = (float*)d_out;

  char* ob = (char*)d_out;
  i8* Xi8 = (i8*)ob;                           // [0, 8M)
  i8* Ci8 = (i8*)(ob + 8ull * 1024 * 1024);    // [8M, 12M)

  char* wsb = (char*)d_ws;
  float* sxA   = (float*)wsb;                  // 64 KB
  float* AxA   = (float*)(wsb + 64 * 1024);    // 64 KB
  float* scA   = (float*)(wsb + 128 * 1024);   // 32 KB
  float* cnormA= (float*)(wsb + 160 * 1024);   // 32 KB
  uint*  scT   = (uint*)(wsb + 192 * 1024);    // 256 B
  uint*  CsT   = (uint*)(wsb + 192 * 1024 + 256);
  unsigned int* bestIdx = (unsigned int*)(wsb + 196 * 1024);  // 64 KB

  const size_t statsBytes = (size_t)MROWS * NTILES * sizeof(uint2);  // 8 MB
  bool fuse = ws_size >= 1024 * 1024 + statsBytes + 65536;
  uint2* stats = fuse ? (uint2*)(wsb + 1024 * 1024)
                      : (uint2*)(ob + 16ull * 1024 * 1024);   // [16M, 24M)

  (void)hipFuncSetAttribute((const void*)k_gemm_min,
                            hipFuncAttributeMaxDynamicSharedMemorySize, 98304);

  k_quant_x<<<4096, 256, 0, stream>>>(x, Xi8, sxA, AxA, scT);
  k_quant_c<<<2048, 256, 0, stream>>>(cb, Ci8, scA, cnormA, scT, CsT);
  k_gemm_min<<<2048, 512, 98304, stream>>>(Xi8, Ci8, scA, cnormA, sxA, stats);
  if (fuse) {
    k_refine_gather<<<4096, 256, 0, stream>>>(x, cb, cnormA, sxA, AxA,
                                              (const float*)scT, (const float*)CsT,
                                              stats, out);
  } else {
    k_refine<<<4096, 256, 0, stream>>>(x, cb, cnormA, sxA, AxA,
                                       (const float*)scT, (const float*)CsT,
                                       stats, bestIdx);
    k_gather<<<4096, 256, 0, stream>>>(cb, bestIdx, out);
  }
}

// Round 11
// 252.654 us; speedup vs baseline: 12.1757x; 12.1757x over previous
//
#include <hip/hip_runtime.h>

// x [16384,512] f32, codebook [8192,512] f32 -> out[n] = codebook[argmin_k ||x_n-c_k||^2]
// bf16 MFMA GEMM, 256(cb)x128(x) blocks, BK=32, 2-deep pipeline, 48KB LDS ->
// 2 blocks/CU x 8 waves = 4 waves/SIMD (occupancy lever). Operand-swapped so argmin
// axis is lane-local; per-lane top-3 + LDS key merge; guaranteed-inclusive fp64
// refine fused with gather.

#define MROWS 16384
#define KCB   8192
#define DDIM  512
#define NKT   16             // K-tiles of BK=32
#define NTILES 64            // stat tiles of 128 cb rows
#define MARGIN 8.0f

typedef unsigned short u16;
typedef unsigned int uint;
typedef __attribute__((ext_vector_type(8))) short bf16x8;
typedef __attribute__((ext_vector_type(4))) float f32x4;

__device__ inline u16 f2bf(float f) {
  unsigned int u = __float_as_uint(f);
  u += 0x7FFFu + ((u >> 16) & 1u);
  return (u16)(u >> 16);
}

__device__ inline void gload16(const void* g, void* l) {
  __builtin_amdgcn_global_load_lds((const __attribute__((address_space(1))) void*)g,
                                   (__attribute__((address_space(3))) void*)l,
                                   16, 0, 0);
}

__device__ inline double shfl_xor_dbl(double v, int m) {
  long long l = __double_as_longlong(v);
  int lo = (int)(l & 0xffffffffLL), hi = (int)(l >> 32);
  lo = __shfl_xor(lo, m, 64);
  hi = __shfl_xor(hi, m, 64);
  return __longlong_as_double(((long long)hi << 32) | (unsigned long long)(unsigned int)lo);
}

__device__ inline float keyval(uint k) {
  uint u = k & 0xFFFFFF80u;
  uint bits = (u & 0x80000000u) ? (u & 0x7FFFFFFFu) : ~u;
  return __uint_as_float(bits);
}

// ---------------- conversion kernels ----------------

__global__ __launch_bounds__(256) void k_conv_x(const float* __restrict__ x,
                                                u16* __restrict__ xb) {
  size_t i = ((size_t)blockIdx.x * 256 + threadIdx.x) * 8;
  float4 a = *(const float4*)(x + i);
  float4 b = *(const float4*)(x + i + 4);
  union { u16 s[8]; uint4 v; } u;
  u.s[0]=f2bf(a.x); u.s[1]=f2bf(a.y); u.s[2]=f2bf(a.z); u.s[3]=f2bf(a.w);
  u.s[4]=f2bf(b.x); u.s[5]=f2bf(b.y); u.s[6]=f2bf(b.z); u.s[7]=f2bf(b.w);
  *(uint4*)(xb + i) = u.v;
}

__global__ __launch_bounds__(256) void k_conv_cb(const float* __restrict__ cb,
                                                 u16* __restrict__ cbb,
                                                 float* __restrict__ cnorm) {
  int k = blockIdx.x * 4 + (threadIdx.x >> 6);
  int lane = threadIdx.x & 63;
  size_t base = (size_t)k * DDIM + lane * 8;
  float4 a = *(const float4*)(cb + base);
  float4 b = *(const float4*)(cb + base + 4);
  union { u16 s[8]; uint4 v; } u;
  u.s[0]=f2bf(a.x); u.s[1]=f2bf(a.y); u.s[2]=f2bf(a.z); u.s[3]=f2bf(a.w);
  u.s[4]=f2bf(b.x); u.s[5]=f2bf(b.y); u.s[6]=f2bf(b.z); u.s[7]=f2bf(b.w);
  *(uint4*)(cbb + base) = u.v;
  float s = a.x*a.x + a.y*a.y + a.z*a.z + a.w*a.w
          + b.x*b.x + b.y*b.y + b.z*b.z + b.w*b.w;
  #pragma unroll
  for (int m = 1; m < 64; m <<= 1) s += __shfl_xor(s, m, 64);
  if (lane == 0) cnorm[k] = s;
}

// ---------------- 256(cb)x128(x) GEMM, BK=32, 2 blocks/CU ----------------
// LDS (u16 elems): buf b at b*12288: A (cb 256x32) at +0, B (x 128x32) at +8192.
// Row layout: row*32 + chunk*8, chunk = src_chunk ^ ((row+(row>>2))&3).

__global__ __launch_bounds__(512, 4) void k_gemm_min(
    const u16* __restrict__ Xbf, const u16* __restrict__ Cbf,
    const float* __restrict__ cnorm, uint2* __restrict__ stats)
{
  extern __shared__ __align__(16) u16 lds[];

  int bid = blockIdx.x;          // 4096 blocks
  int xcd = bid & 7;
  int j   = bid >> 3;            // 0..511
  int mTile = xcd * 16 + (j & 15);  // x tiles 0..127
  int nTile = j >> 4;               // cb tiles 0..31
  int rowBase = mTile * 128;     // x rows
  int colBase = nTile * 256;     // cb rows

  int tid = threadIdx.x;
  int lane = tid & 63;
  int wv = tid >> 6;     // 0..7
  int wr = wv & 3;       // cb quarter (M)
  int wc = wv >> 2;      // x half (N)
  int grp = lane >> 4;
  int l15 = lane & 15;

  // staging sources (inverse-swizzled 16B chunks), kt-invariant bases
  const int ar = tid >> 2;                       // A row 0..127 (f=tid), +128 for f=tid+512
  const int ac = ((tid & 3) ^ ((ar + (ar >> 2)) & 3)) << 3;
  const u16* pA = Cbf + (size_t)(colBase + ar) * DDIM + ac;   // rows 0-127 & +128 share swizzle
  const u16* pB = Xbf + (size_t)(rowBase + ar) * DDIM + ac;   // B rows 0..127

  // reader LDS element offsets (kt-invariant)
  int offA[4], offX[4];
  #pragma unroll
  for (int i = 0; i < 4; ++i) {
    int rA = wr * 64 + i * 16 + l15;
    offA[i] = rA * 32 + ((grp ^ ((rA + (rA >> 2)) & 3)) << 3);
    int rX = wc * 64 + i * 16 + l15;
    offX[i] = 8192 + rX * 32 + ((grp ^ ((rX + (rX >> 2)) & 3)) << 3);
  }

  f32x4 acc[4][4];
  #pragma unroll
  for (int mi = 0; mi < 4; ++mi)
    #pragma unroll
    for (int ni = 0; ni < 4; ++ni)
      acc[mi][ni] = (f32x4){0.f, 0.f, 0.f, 0.f};

#define STAGE(b_, T)                                                          \
  {                                                                           \
    u16* Ad = lds + (b_) * 12288;                                             \
    gload16(pA + (T) * 32,               (void*)(Ad + tid * 8));              \
    gload16(pA + 65536 + (T) * 32,       (void*)(Ad + 4096 + tid * 8));       \
    gload16(pB + (T) * 32,               (void*)(Ad + 8192 + tid * 8));       \
  }

  STAGE(0, 0);
  STAGE(1, 1);
  __syncthreads();               // prologue drain

  int cur = 0;
  for (int kt = 0; kt < NKT; ++kt) {
    const u16* base = lds + cur * 12288;
    bf16x8 cF[4], xF[4];
    #pragma unroll
    for (int mi = 0; mi < 4; ++mi) cF[mi] = *(const bf16x8*)&base[offA[mi]];
    #pragma unroll
    for (int ni = 0; ni < 4; ++ni) xF[ni] = *(const bf16x8*)&base[offX[ni]];
    __builtin_amdgcn_s_setprio(1);
    #pragma unroll
    for (int mi = 0; mi < 4; ++mi)
      #pragma unroll
      for (int ni = 0; ni < 4; ++ni)
        acc[mi][ni] = __builtin_amdgcn_mfma_f32_16x16x32_bf16(cF[mi], xF[ni], acc[mi][ni], 0, 0, 0);
    __builtin_amdgcn_s_setprio(0);
    __syncthreads();             // frees buf cur; drains stage issued LAST iteration
    if (kt + 2 < NKT) STAGE(cur, kt + 2);
    cur ^= 1;
  }
#undef STAGE

  // ---- epilogue: per-lane top-3 over wave's 64 cb rows ----
  // D[m=cb][n=x]: x-row = lane&15, cb = (lane>>4)*4 + reg
#define INS(st1, st2, st3, kx)                                     \
  { uint kk_ = (kx);                                               \
    bool lt1 = kk_ < st1, lt2 = kk_ < st2, lt3 = kk_ < st3;        \
    st3 = lt3 ? (lt2 ? st2 : kk_) : st3;                           \
    st2 = lt2 ? (lt1 ? st1 : kk_) : st2;                           \
    st1 = lt1 ? kk_ : st1; }

  uint t1[4], t2[4], t3[4];
  #pragma unroll
  for (int ni = 0; ni < 4; ++ni) { t1[ni] = 0xFFFFFFFFu; t2[ni] = 0xFFFFFFFFu; t3[ni] = 0xFFFFFFFFu; }

  const uint tagBase = (uint)((wr & 1) * 64);   // position within 128-row stat tile
  #pragma unroll
  for (int mi = 0; mi < 4; ++mi) {
    float cnv[4];
    *(float4*)cnv = *(const float4*)&cnorm[colBase + wr * 64 + mi * 16 + grp * 4];
    #pragma unroll
    for (int ni = 0; ni < 4; ++ni) {
      #pragma unroll
      for (int rg = 0; rg < 4; ++rg) {
        float v = cnv[rg] - 2.0f * acc[mi][ni][rg];
        uint u = __float_as_uint(v);
        u = ((int)u < 0) ? ~u : (u | 0x80000000u);
        uint key = (u & 0xFFFFFF80u) | (tagBase + (uint)(mi * 16 + grp * 4 + rg));
        INS(t1[ni], t2[ni], t3[ni], key);
      }
    }
  }
  #pragma unroll
  for (int ni = 0; ni < 4; ++ni) {
    #pragma unroll
    for (int mk = 16; mk <= 32; mk <<= 1) {
      uint o1 = (uint)__shfl_xor((int)t1[ni], mk, 64);
      uint o2 = (uint)__shfl_xor((int)t2[ni], mk, 64);
      uint o3 = (uint)__shfl_xor((int)t3[ni], mk, 64);
      INS(t1[ni], t2[ni], t3[ni], o1);
      INS(t1[ni], t2[ni], t3[ni], o2);
      INS(t1[ni], t2[ni], t3[ni], o3);
    }
  }

  // LDS key-merge across the cb-quarter wave pairs (wr 0+1 -> tile 0, 2+3 -> tile 1)
  uint* scK = (uint*)lds;        // [4 wr][128 xloc][3] = 6 KB (all GEMM reads done)
  if (grp == 0) {
    #pragma unroll
    for (int ni = 0; ni < 4; ++ni) {
      int xloc = wc * 64 + ni * 16 + l15;
      uint* p = &scK[(wr * 128 + xloc) * 3];
      p[0] = t1[ni]; p[1] = t2[ni]; p[2] = t3[ni];
    }
  }
  __syncthreads();
  if (tid < 256) {
    int xr = tid & 127;
    int s  = tid >> 7;           // stat tile within block
    const uint* pa = &scK[((2 * s) * 128 + xr) * 3];
    const uint* pb = &scK[((2 * s + 1) * 128 + xr) * 3];
    uint a1 = pa[0], a2 = pa[1], a3 = pa[2];
    #pragma unroll
    for (int z = 0; z < 3; ++z) INS(a1, a2, a3, pb[z]);
    float v1 = keyval(a1), v2 = keyval(a2), v3 = keyval(a3);
    uint i1 = a1 & 127u, i2 = a2 & 127u;
    uint d2 = min(255u, (uint)((v2 - v1) * 4.0f));   // floor -> conservative-low
    uint d3 = min(255u, (uint)((v3 - v1) * 4.0f));
    uint2 st;
    st.x = __float_as_uint(v1);
    st.y = i1 | (i2 << 7) | (d2 << 14) | (d3 << 22);
    stats[(size_t)(rowBase + xr) * NTILES + nTile * 2 + s] = st;
  }
#undef INS
}

// ---------------- fp64 refinement core ----------------

__device__ inline void eval64(const float4& xa, const float4& xb,
                              const float* __restrict__ cb, int col,
                              double& best, int& bi, int lane) {
  const float* cr = cb + (size_t)col * DDIM + lane * 8;
  float4 ca = *(const float4*)cr;
  float4 cv = *(const float4*)(cr + 4);
  double s = 0.0, d;
  d = (double)xa.x - (double)ca.x; s += d*d;
  d = (double)xa.y - (double)ca.y; s += d*d;
  d = (double)xa.z - (double)ca.z; s += d*d;
  d = (double)xa.w - (double)ca.w; s += d*d;
  d = (double)xb.x - (double)cv.x; s += d*d;
  d = (double)xb.y - (double)cv.y; s += d*d;
  d = (double)xb.z - (double)cv.z; s += d*d;
  d = (double)xb.w - (double)cv.w; s += d*d;
  #pragma unroll
  for (int m = 1; m < 64; m <<= 1) s += shfl_xor_dbl(s, m);
  if (s < best || (s == best && col < bi)) { best = s; bi = col; }
}

__device__ inline int refine_row(int n, int lane,
                                 const float* __restrict__ x, const float* __restrict__ cb,
                                 const float* __restrict__ cnorm,
                                 const uint2* __restrict__ stats) {
  uint2 st = stats[(size_t)n * NTILES + lane];   // lane t owns stat tile t
  float m1 = __uint_as_float(st.x);
  int   i1 = st.y & 127, i2 = (st.y >> 7) & 127;
  float m2 = m1 + ((st.y >> 14) & 255u) * 0.25f;
  float m3 = m1 + ((st.y >> 22) & 255u) * 0.25f;
  float g = m1;
  #pragma unroll
  for (int m = 1; m < 64; m <<= 1) g = fminf(g, __shfl_xor(g, m, 64));
  float T = g + MARGIN;
  unsigned long long q1 = __ballot(m1 <= T);
  unsigned long long q2 = __ballot(m2 <= T);
  unsigned long long qr = __ballot(m3 <= T);

  const float* xr = x + (size_t)n * DDIM;
  float4 xa = *(const float4*)(xr + lane * 8);
  float4 xb = *(const float4*)(xr + lane * 8 + 4);

  double best = 1e300;
  int bi = 0x7fffffff;

  while (q1) {
    int t = __ffsll(q1) - 1; q1 &= q1 - 1;
    int col = t * 128 + __shfl(i1, t, 64);
    eval64(xa, xb, cb, col, best, bi, lane);
  }
  while (q2) {
    int t = __ffsll(q2) - 1; q2 &= q2 - 1;
    int col = t * 128 + __shfl(i2, t, 64);
    eval64(xa, xb, cb, col, best, bi, lane);
  }
  while (qr) {
    int t = __ffsll(qr) - 1; qr &= qr - 1;
    for (int c2 = 0; c2 < 128; ++c2) {
      int col2 = t * 128 + c2;
      const float* cr = cb + (size_t)col2 * DDIM + lane * 8;
      float4 ca = *(const float4*)cr;
      float4 cv = *(const float4*)(cr + 4);
      float p = xa.x*ca.x + xa.y*ca.y + xa.z*ca.z + xa.w*ca.w
              + xb.x*cv.x + xb.y*cv.y + xb.z*cv.z + xb.w*cv.w;
      #pragma unroll
      for (int m = 1; m < 64; m <<= 1) p += __shfl_xor(p, m, 64);
      float s32 = cnorm[col2] - 2.0f * p;
      if (s32 <= T) {
        double s = 0.0, dd;
        dd = (double)xa.x - (double)ca.x; s += dd*dd;
        dd = (double)xa.y - (double)ca.y; s += dd*dd;
        dd = (double)xa.z - (double)ca.z; s += dd*dd;
        dd = (double)xa.w - (double)ca.w; s += dd*dd;
        dd = (double)xb.x - (double)cv.x; s += dd*dd;
        dd = (double)xb.y - (double)cv.y; s += dd*dd;
        dd = (double)xb.z - (double)cv.z; s += dd*dd;
        dd = (double)xb.w - (double)cv.w; s += dd*dd;
        #pragma unroll
        for (int m = 1; m < 64; m <<= 1) s += shfl_xor_dbl(s, m);
        if (s < best || (s == best && col2 < bi)) { best = s; bi = col2; }
      }
    }
  }
  return bi;
}

__global__ __launch_bounds__(256) void k_refine(
    const float* __restrict__ x, const float* __restrict__ cb,
    const float* __restrict__ cnorm, const uint2* __restrict__ stats,
    unsigned int* __restrict__ bestOut)
{
  int n = blockIdx.x * 4 + (threadIdx.x >> 6);
  int lane = threadIdx.x & 63;
  int bi = refine_row(n, lane, x, cb, cnorm, stats);
  if (lane == 0) bestOut[n] = (unsigned int)bi;
}

__global__ __launch_bounds__(256) void k_refine_gather(
    const float* __restrict__ x, const float* __restrict__ cb,
    const float* __restrict__ cnorm, const uint2* __restrict__ stats,
    float* __restrict__ out)
{
  int n = blockIdx.x * 4 + (threadIdx.x >> 6);
  int lane = threadIdx.x & 63;
  int bi = refine_row(n, lane, x, cb, cnorm, stats);
  const float4* s = (const float4*)(cb + (size_t)bi * DDIM);
  float4* dp = (float4*)(out + (size_t)n * DDIM);
  dp[lane * 2]     = s[lane * 2];
  dp[lane * 2 + 1] = s[lane * 2 + 1];
}

__global__ __launch_bounds__(256) void k_gather(const float* __restrict__ cb,
                                                const unsigned int* __restrict__ bestIdx,
                                                float* __restrict__ out) {
  int n = blockIdx.x * 4 + (threadIdx.x >> 6);
  int lane = threadIdx.x & 63;
  unsigned int b = bestIdx[n];
  const float4* s = (const float4*)(cb + (size_t)b * DDIM);
  float4* dp = (float4*)(out + (size_t)n * DDIM);
  dp[lane * 2]     = s[lane * 2];
  dp[lane * 2 + 1] = s[lane * 2 + 1];
}

// ---------------- launch ----------------

extern "C" void kernel_launch(void* const* d_in, const int* in_sizes, int n_in,
                              void* d_out, int out_size, void* d_ws, size_t ws_size,
                              hipStream_t stream) {
  const float* x  = (const float*)d_in[0];   // [16384, 512]
  const float* cb = (const float*)d_in[1];   // [8192, 512]
  float* out = (float*)d_out;

  char* ob = (char*)d_out;
  u16* Xbf = (u16*)ob;                          // [0,16M)
  u16* Cbf = (u16*)(ob + 16ull * 1024 * 1024);  // [16M,24M)

  char* wsb = (char*)d_ws;
  float* cnorm = (float*)wsb;                               // 32 KB
  unsigned int* bestIdx = (unsigned int*)(wsb + 32 * 1024); // 64 KB

  const size_t statsBytes = (size_t)MROWS * NTILES * sizeof(uint2);  // 8 MB
  bool fuse = ws_size >= 96 * 1024 + statsBytes;
  uint2* stats = fuse ? (uint2*)(wsb + 96 * 1024)
                      : (uint2*)(ob + 24ull * 1024 * 1024);

  (void)hipFuncSetAttribute((const void*)k_gemm_min,
                            hipFuncAttributeMaxDynamicSharedMemorySize, 49152);

  k_conv_x  <<<4096, 256, 0, stream>>>(x, Xbf);
  k_conv_cb <<<2048, 256, 0, stream>>>(cb, Cbf, cnorm);
  k_gemm_min<<<4096, 512, 49152, stream>>>(Xbf, Cbf, cnorm, stats);
  if (fuse) {
    k_refine_gather<<<4096, 256, 0, stream>>>(x, cb, cnorm, stats, out);
  } else {
    k_refine<<<4096, 256, 0, stream>>>(x, cb, cnorm, stats, bestIdx);
    k_gather<<<4096, 256, 0, stream>>>(cb, bestIdx, out);
  }
}

// Round 12
// 249.896 us; speedup vs baseline: 12.3101x; 1.0110x over previous
//
#include <hip/hip_runtime.h>

// x [16384,512] f32, codebook [8192,512] f32 -> out[n] = codebook[argmin_k ||x_n-c_k||^2]
// bf16 MFMA GEMM, 256(cb)x128(x) blocks, BK=32, 2-deep pipeline, 48KB LDS ->
// 2 blocks/CU x 8 waves = 4 waves/SIMD. PAIR-LINE LDS layout: row pairs share a
// 128-B line (8x16B slots, slot' = slot ^ (line&7)) -> every line spans all 32 banks
// (the layout that measured 0 conflicts in earlier rounds). Operand-swapped so argmin
// axis is lane-local; per-lane top-3 + LDS key merge; guaranteed-inclusive fp64
// refine fused with gather.

#define MROWS 16384
#define KCB   8192
#define DDIM  512
#define NKT   16             // K-tiles of BK=32
#define NTILES 64            // stat tiles of 128 cb rows
#define MARGIN 8.0f

typedef unsigned short u16;
typedef unsigned int uint;
typedef __attribute__((ext_vector_type(8))) short bf16x8;
typedef __attribute__((ext_vector_type(4))) float f32x4;

__device__ inline u16 f2bf(float f) {
  unsigned int u = __float_as_uint(f);
  u += 0x7FFFu + ((u >> 16) & 1u);
  return (u16)(u >> 16);
}

__device__ inline void gload16(const void* g, void* l) {
  __builtin_amdgcn_global_load_lds((const __attribute__((address_space(1))) void*)g,
                                   (__attribute__((address_space(3))) void*)l,
                                   16, 0, 0);
}

__device__ inline double shfl_xor_dbl(double v, int m) {
  long long l = __double_as_longlong(v);
  int lo = (int)(l & 0xffffffffLL), hi = (int)(l >> 32);
  lo = __shfl_xor(lo, m, 64);
  hi = __shfl_xor(hi, m, 64);
  return __longlong_as_double(((long long)hi << 32) | (unsigned long long)(unsigned int)lo);
}

__device__ inline float keyval(uint k) {
  uint u = k & 0xFFFFFF80u;
  uint bits = (u & 0x80000000u) ? (u & 0x7FFFFFFFu) : ~u;
  return __uint_as_float(bits);
}

// ---------------- conversion kernels ----------------

__global__ __launch_bounds__(256) void k_conv_x(const float* __restrict__ x,
                                                u16* __restrict__ xb) {
  size_t i = ((size_t)blockIdx.x * 256 + threadIdx.x) * 8;
  float4 a = *(const float4*)(x + i);
  float4 b = *(const float4*)(x + i + 4);
  union { u16 s[8]; uint4 v; } u;
  u.s[0]=f2bf(a.x); u.s[1]=f2bf(a.y); u.s[2]=f2bf(a.z); u.s[3]=f2bf(a.w);
  u.s[4]=f2bf(b.x); u.s[5]=f2bf(b.y); u.s[6]=f2bf(b.z); u.s[7]=f2bf(b.w);
  *(uint4*)(xb + i) = u.v;
}

__global__ __launch_bounds__(256) void k_conv_cb(const float* __restrict__ cb,
                                                 u16* __restrict__ cbb,
                                                 float* __restrict__ cnorm) {
  int k = blockIdx.x * 4 + (threadIdx.x >> 6);
  int lane = threadIdx.x & 63;
  size_t base = (size_t)k * DDIM + lane * 8;
  float4 a = *(const float4*)(cb + base);
  float4 b = *(const float4*)(cb + base + 4);
  union { u16 s[8]; uint4 v; } u;
  u.s[0]=f2bf(a.x); u.s[1]=f2bf(a.y); u.s[2]=f2bf(a.z); u.s[3]=f2bf(a.w);
  u.s[4]=f2bf(b.x); u.s[5]=f2bf(b.y); u.s[6]=f2bf(b.z); u.s[7]=f2bf(b.w);
  *(uint4*)(cbb + base) = u.v;
  float s = a.x*a.x + a.y*a.y + a.z*a.z + a.w*a.w
          + b.x*b.x + b.y*b.y + b.z*b.z + b.w*b.w;
  #pragma unroll
  for (int m = 1; m < 64; m <<= 1) s += __shfl_xor(s, m, 64);
  if (lane == 0) cnorm[k] = s;
}

// ---------------- 256(cb)x128(x) GEMM, BK=32, pair-line LDS ----------------
// LDS (u16 elems): buf b at b*12288: A (cb 256x32) at +0 (128 lines of 128B),
// B (x 128x32) at +8192 (64 lines). Line R holds rows {2R, 2R+1}; slot s =
// (row&1)*4 + chunk stored at s' = s ^ (R&7).

__global__ __launch_bounds__(512, 4) void k_gemm_min(
    const u16* __restrict__ Xbf, const u16* __restrict__ Cbf,
    const float* __restrict__ cnorm, uint2* __restrict__ stats)
{
  extern __shared__ __align__(16) u16 lds[];

  int bid = blockIdx.x;          // 4096 blocks
  int xcd = bid & 7;
  int j   = bid >> 3;            // 0..511
  int mTile = xcd * 16 + (j & 15);  // x tiles 0..127
  int nTile = j >> 4;               // cb tiles 0..31
  int rowBase = mTile * 128;     // x rows
  int colBase = nTile * 256;     // cb rows

  int tid = threadIdx.x;
  int lane = tid & 63;
  int wv = tid >> 6;     // 0..7
  int wr = wv & 3;       // cb quarter (M)
  int wc = wv >> 2;      // x half (N)
  int grp = lane >> 4;
  int l15 = lane & 15;

  // staging sources: dest byte tid*16 = line R0=tid>>3, slot' tid&7;
  // inverse map -> source (row, chunk)
  const int R0 = tid >> 3;
  const int s0 = (tid & 7) ^ (R0 & 7);
  const int row_st = 2 * R0 + (s0 >> 2);
  const int ch_st  = (s0 & 3) << 3;            // element offset in row
  const u16* pA = Cbf + (size_t)(colBase + row_st) * DDIM + ch_st;
  const u16* pB = Xbf + (size_t)(rowBase + row_st) * DDIM + ch_st;

  // reader LDS element offsets (kt-invariant); lane swizzle shared by A and X
  const int lswz = (((((l15 & 1) << 2) | grp) ^ ((l15 >> 1) & 7)) << 3);
  int offA[4], offX[4];
  #pragma unroll
  for (int i = 0; i < 4; ++i) {
    int rA = wr * 64 + i * 16 + l15;
    offA[i] = (rA >> 1) * 64 + lswz;
    int rX = wc * 64 + i * 16 + l15;
    offX[i] = 8192 + (rX >> 1) * 64 + lswz;
  }

  f32x4 acc[4][4];
  #pragma unroll
  for (int mi = 0; mi < 4; ++mi)
    #pragma unroll
    for (int ni = 0; ni < 4; ++ni)
      acc[mi][ni] = (f32x4){0.f, 0.f, 0.f, 0.f};

#define STAGE(b_, T)                                                          \
  {                                                                           \
    u16* Ad = lds + (b_) * 12288;                                             \
    gload16(pA + (T) * 32,               (void*)(Ad + tid * 8));              \
    gload16(pA + 65536 + (T) * 32,       (void*)(Ad + 4096 + tid * 8));       \
    gload16(pB + (T) * 32,               (void*)(Ad + 8192 + tid * 8));       \
  }

  STAGE(0, 0);
  STAGE(1, 1);
  __syncthreads();               // prologue drain

  int cur = 0;
  for (int kt = 0; kt < NKT; ++kt) {
    const u16* base = lds + cur * 12288;
    bf16x8 cF[4], xF[4];
    #pragma unroll
    for (int mi = 0; mi < 4; ++mi) cF[mi] = *(const bf16x8*)&base[offA[mi]];
    #pragma unroll
    for (int ni = 0; ni < 4; ++ni) xF[ni] = *(const bf16x8*)&base[offX[ni]];
    __builtin_amdgcn_s_setprio(1);
    #pragma unroll
    for (int mi = 0; mi < 4; ++mi)
      #pragma unroll
      for (int ni = 0; ni < 4; ++ni)
        acc[mi][ni] = __builtin_amdgcn_mfma_f32_16x16x32_bf16(cF[mi], xF[ni], acc[mi][ni], 0, 0, 0);
    __builtin_amdgcn_s_setprio(0);
    __syncthreads();             // frees buf cur; drains stage issued LAST iteration
    if (kt + 2 < NKT) STAGE(cur, kt + 2);
    cur ^= 1;
  }
#undef STAGE

  // ---- epilogue: per-lane top-3 over wave's 64 cb rows ----
  // D[m=cb][n=x]: x-row = lane&15, cb = (lane>>4)*4 + reg
#define INS(st1, st2, st3, kx)                                     \
  { uint kk_ = (kx);                                               \
    bool lt1 = kk_ < st1, lt2 = kk_ < st2, lt3 = kk_ < st3;        \
    st3 = lt3 ? (lt2 ? st2 : kk_) : st3;                           \
    st2 = lt2 ? (lt1 ? st1 : kk_) : st2;                           \
    st1 = lt1 ? kk_ : st1; }

  uint t1[4], t2[4], t3[4];
  #pragma unroll
  for (int ni = 0; ni < 4; ++ni) { t1[ni] = 0xFFFFFFFFu; t2[ni] = 0xFFFFFFFFu; t3[ni] = 0xFFFFFFFFu; }

  const uint tagBase = (uint)((wr & 1) * 64);   // position within 128-row stat tile
  #pragma unroll
  for (int mi = 0; mi < 4; ++mi) {
    float cnv[4];
    *(float4*)cnv = *(const float4*)&cnorm[colBase + wr * 64 + mi * 16 + grp * 4];
    #pragma unroll
    for (int ni = 0; ni < 4; ++ni) {
      #pragma unroll
      for (int rg = 0; rg < 4; ++rg) {
        float v = cnv[rg] - 2.0f * acc[mi][ni][rg];
        uint u = __float_as_uint(v);
        u = ((int)u < 0) ? ~u : (u | 0x80000000u);
        uint key = (u & 0xFFFFFF80u) | (tagBase + (uint)(mi * 16 + grp * 4 + rg));
        INS(t1[ni], t2[ni], t3[ni], key);
      }
    }
  }
  #pragma unroll
  for (int ni = 0; ni < 4; ++ni) {
    #pragma unroll
    for (int mk = 16; mk <= 32; mk <<= 1) {
      uint o1 = (uint)__shfl_xor((int)t1[ni], mk, 64);
      uint o2 = (uint)__shfl_xor((int)t2[ni], mk, 64);
      uint o3 = (uint)__shfl_xor((int)t3[ni], mk, 64);
      INS(t1[ni], t2[ni], t3[ni], o1);
      INS(t1[ni], t2[ni], t3[ni], o2);
      INS(t1[ni], t2[ni], t3[ni], o3);
    }
  }

  // LDS key-merge across the cb-quarter wave pairs (wr 0+1 -> tile 0, 2+3 -> tile 1)
  uint* scK = (uint*)lds;        // [4 wr][128 xloc][3] = 6 KB (all GEMM reads done)
  if (grp == 0) {
    #pragma unroll
    for (int ni = 0; ni < 4; ++ni) {
      int xloc = wc * 64 + ni * 16 + l15;
      uint* p = &scK[(wr * 128 + xloc) * 3];
      p[0] = t1[ni]; p[1] = t2[ni]; p[2] = t3[ni];
    }
  }
  __syncthreads();
  if (tid < 256) {
    int xr = tid & 127;
    int s  = tid >> 7;           // stat tile within block
    const uint* pa = &scK[((2 * s) * 128 + xr) * 3];
    const uint* pb = &scK[((2 * s + 1) * 128 + xr) * 3];
    uint a1 = pa[0], a2 = pa[1], a3 = pa[2];
    #pragma unroll
    for (int z = 0; z < 3; ++z) INS(a1, a2, a3, pb[z]);
    float v1 = keyval(a1), v2 = keyval(a2), v3 = keyval(a3);
    uint i1 = a1 & 127u, i2 = a2 & 127u;
    uint d2 = min(255u, (uint)((v2 - v1) * 4.0f));   // floor -> conservative-low
    uint d3 = min(255u, (uint)((v3 - v1) * 4.0f));
    uint2 st;
    st.x = __float_as_uint(v1);
    st.y = i1 | (i2 << 7) | (d2 << 14) | (d3 << 22);
    stats[(size_t)(rowBase + xr) * NTILES + nTile * 2 + s] = st;
  }
#undef INS
}

// ---------------- fp64 refinement core ----------------

__device__ inline void eval64(const float4& xa, const float4& xb,
                              const float* __restrict__ cb, int col,
                              double& best, int& bi, int lane) {
  const float* cr = cb + (size_t)col * DDIM + lane * 8;
  float4 ca = *(const float4*)cr;
  float4 cv = *(const float4*)(cr + 4);
  double s = 0.0, d;
  d = (double)xa.x - (double)ca.x; s += d*d;
  d = (double)xa.y - (double)ca.y; s += d*d;
  d = (double)xa.z - (double)ca.z; s += d*d;
  d = (double)xa.w - (double)ca.w; s += d*d;
  d = (double)xb.x - (double)cv.x; s += d*d;
  d = (double)xb.y - (double)cv.y; s += d*d;
  d = (double)xb.z - (double)cv.z; s += d*d;
  d = (double)xb.w - (double)cv.w; s += d*d;
  #pragma unroll
  for (int m = 1; m < 64; m <<= 1) s += shfl_xor_dbl(s, m);
  if (s < best || (s == best && col < bi)) { best = s; bi = col; }
}

__device__ inline int refine_row(int n, int lane,
                                 const float* __restrict__ x, const float* __restrict__ cb,
                                 const float* __restrict__ cnorm,
                                 const uint2* __restrict__ stats) {
  uint2 st = stats[(size_t)n * NTILES + lane];   // lane t owns stat tile t
  float m1 = __uint_as_float(st.x);
  int   i1 = st.y & 127, i2 = (st.y >> 7) & 127;
  float m2 = m1 + ((st.y >> 14) & 255u) * 0.25f;
  float m3 = m1 + ((st.y >> 22) & 255u) * 0.25f;
  float g = m1;
  #pragma unroll
  for (int m = 1; m < 64; m <<= 1) g = fminf(g, __shfl_xor(g, m, 64));
  float T = g + MARGIN;
  unsigned long long q1 = __ballot(m1 <= T);
  unsigned long long q2 = __ballot(m2 <= T);
  unsigned long long qr = __ballot(m3 <= T);

  const float* xr = x + (size_t)n * DDIM;
  float4 xa = *(const float4*)(xr + lane * 8);
  float4 xb = *(const float4*)(xr + lane * 8 + 4);

  double best = 1e300;
  int bi = 0x7fffffff;

  while (q1) {
    int t = __ffsll(q1) - 1; q1 &= q1 - 1;
    int col = t * 128 + __shfl(i1, t, 64);
    eval64(xa, xb, cb, col, best, bi, lane);
  }
  while (q2) {
    int t = __ffsll(q2) - 1; q2 &= q2 - 1;
    int col = t * 128 + __shfl(i2, t, 64);
    eval64(xa, xb, cb, col, best, bi, lane);
  }
  while (qr) {
    int t = __ffsll(qr) - 1; qr &= qr - 1;
    for (int c2 = 0; c2 < 128; ++c2) {
      int col2 = t * 128 + c2;
      const float* cr = cb + (size_t)col2 * DDIM + lane * 8;
      float4 ca = *(const float4*)cr;
      float4 cv = *(const float4*)(cr + 4);
      float p = xa.x*ca.x + xa.y*ca.y + xa.z*ca.z + xa.w*ca.w
              + xb.x*cv.x + xb.y*cv.y + xb.z*cv.z + xb.w*cv.w;
      #pragma unroll
      for (int m = 1; m < 64; m <<= 1) p += __shfl_xor(p, m, 64);
      float s32 = cnorm[col2] - 2.0f * p;
      if (s32 <= T) {
        double s = 0.0, dd;
        dd = (double)xa.x - (double)ca.x; s += dd*dd;
        dd = (double)xa.y - (double)ca.y; s += dd*dd;
        dd = (double)xa.z - (double)ca.z; s += dd*dd;
        dd = (double)xa.w - (double)ca.w; s += dd*dd;
        dd = (double)xb.x - (double)cv.x; s += dd*dd;
        dd = (double)xb.y - (double)cv.y; s += dd*dd;
        dd = (double)xb.z - (double)cv.z; s += dd*dd;
        dd = (double)xb.w - (double)cv.w; s += dd*dd;
        #pragma unroll
        for (int m = 1; m < 64; m <<= 1) s += shfl_xor_dbl(s, m);
        if (s < best || (s == best && col2 < bi)) { best = s; bi = col2; }
      }
    }
  }
  return bi;
}

__global__ __launch_bounds__(256) void k_refine(
    const float* __restrict__ x, const float* __restrict__ cb,
    const float* __restrict__ cnorm, const uint2* __restrict__ stats,
    unsigned int* __restrict__ bestOut)
{
  int n = blockIdx.x * 4 + (threadIdx.x >> 6);
  int lane = threadIdx.x & 63;
  int bi = refine_row(n, lane, x, cb, cnorm, stats);
  if (lane == 0) bestOut[n] = (unsigned int)bi;
}

__global__ __launch_bounds__(256) void k_refine_gather(
    const float* __restrict__ x, const float* __restrict__ cb,
    const float* __restrict__ cnorm, const uint2* __restrict__ stats,
    float* __restrict__ out)
{
  int n = blockIdx.x * 4 + (threadIdx.x >> 6);
  int lane = threadIdx.x & 63;
  int bi = refine_row(n, lane, x, cb, cnorm, stats);
  const float4* s = (const float4*)(cb + (size_t)bi * DDIM);
  float4* dp = (float4*)(out + (size_t)n * DDIM);
  dp[lane * 2]     = s[lane * 2];
  dp[lane * 2 + 1] = s[lane * 2 + 1];
}

__global__ __launch_bounds__(256) void k_gather(const float* __restrict__ cb,
                                                const unsigned int* __restrict__ bestIdx,
                                                float* __restrict__ out) {
  int n = blockIdx.x * 4 + (threadIdx.x >> 6);
  int lane = threadIdx.x & 63;
  unsigned int b = bestIdx[n];
  const float4* s = (const float4*)(cb + (size_t)b * DDIM);
  float4* dp = (float4*)(out + (size_t)n * DDIM);
  dp[lane * 2]     = s[lane * 2];
  dp[lane * 2 + 1] = s[lane * 2 + 1];
}

// ---------------- launch ----------------

extern "C" void kernel_launch(void* const* d_in, const int* in_sizes, int n_in,
                              void* d_out, int out_size, void* d_ws, size_t ws_size,
                              hipStream_t stream) {
  const float* x  = (const float*)d_in[0];   // [16384, 512]
  const float* cb = (const float*)d_in[1];   // [8192, 512]
  float* out = (float*)d_out;

  char* ob = (char*)d_out;
  u16* Xbf = (u16*)ob;                          // [0,16M)
  u16* Cbf = (u16*)(ob + 16ull * 1024 * 1024);  // [16M,24M)

  char* wsb = (char*)d_ws;
  float* cnorm = (float*)wsb;                               // 32 KB
  unsigned int* bestIdx = (unsigned int*)(wsb + 32 * 1024); // 64 KB

  const size_t statsBytes = (size_t)MROWS * NTILES * sizeof(uint2);  // 8 MB
  bool fuse = ws_size >= 96 * 1024 + statsBytes;
  uint2* stats = fuse ? (uint2*)(wsb + 96 * 1024)
                      : (uint2*)(ob + 24ull * 1024 * 1024);

  (void)hipFuncSetAttribute((const void*)k_gemm_min,
                            hipFuncAttributeMaxDynamicSharedMemorySize, 49152);

  k_conv_x  <<<4096, 256, 0, stream>>>(x, Xbf);
  k_conv_cb <<<2048, 256, 0, stream>>>(cb, Cbf, cnorm);
  k_gemm_min<<<4096, 512, 49152, stream>>>(Xbf, Cbf, cnorm, stats);
  if (fuse) {
    k_refine_gather<<<4096, 256, 0, stream>>>(x, cb, cnorm, stats, out);
  } else {
    k_refine<<<4096, 256, 0, stream>>>(x, cb, cnorm, stats, bestIdx);
    k_gather<<<4096, 256, 0, stream>>>(cb, bestIdx, out);
  }
}